// Round 9
// baseline (241.585 us; speedup 1.0000x reference)
//
#include <hip/hip_runtime.h>
#include <cstdint>
#include <cstddef>

// Pipeline v14. B=4, T=2048, D=1024, H=16, HD=64. Inputs fp32, output fp32.
// R9: counted-vmcnt 3-buffer pipeline (T4) in both bf16 GEMMs:
//   stage(t+2) -> compute(t) -> s_waitcnt vmcnt(4) -> raw s_barrier.
//   Tile t+1's loads are guaranteed landed (FIFO oldest-first); tile t+2's
//   4 loads stay in flight ACROSS the barrier (never drain to 0 mid-loop).
//   3 rotating buffers (48KB LDS); tail iterations use vmcnt(0).
// attn byte-identical to R8 (single structural change per round).

typedef __bf16 bf16;
typedef __bf16 bf16x4 __attribute__((ext_vector_type(4)));
typedef __bf16 bf16x8 __attribute__((ext_vector_type(8)));
typedef float  f32x4  __attribute__((ext_vector_type(4)));
typedef float  fvec4  __attribute__((ext_vector_type(4)));
typedef unsigned u32x2 __attribute__((ext_vector_type(2)));

typedef __attribute__((address_space(1))) const void global_cv;
typedef __attribute__((address_space(3))) void lds_v;

#define MFMA16(a, b, c) __builtin_amdgcn_mfma_f32_16x16x32_bf16((a), (b), (c), 0, 0, 0)

// Q scale: 1/sqrt(64) * log2(e)  (softmax done in exp2 domain)
#define QSCALE 0.18033688f

__device__ __forceinline__ void async_ld16(const bf16* g, bf16* l) {
  __builtin_amdgcn_global_load_lds((global_cv*)g, (lds_v*)l, 16, 0, 0);
}

// XOR chunk swizzle for [rows][64] bf16 LDS tiles (attn staging + frag reads).
__device__ __forceinline__ int swz_off(int row, int col) {
  int sr = (row & 7) ^ ((row >> 3) & 7);
  return row * 64 + ((((col >> 3) ^ sr) & 7) * 8) + (col & 7);
}

// packed f32x2 -> bf16x2
__device__ __forceinline__ unsigned cvt_pk(float lo, float hi) {
  unsigned r;
  asm("v_cvt_pk_bf16_f32 %0, %1, %2" : "=v"(r) : "v"(lo), "v"(hi));
  return r;
}

// exact v_exp_f32 (2^x), no libm fixup path
__device__ __forceinline__ float exp2_fast(float x) {
  float r;
  asm("v_exp_f32 %0, %1" : "=v"(r) : "v"(x));
  return r;
}

__device__ __forceinline__ bf16x8 cvt8(const float* p) {
  fvec4 u = *(const fvec4*)p;
  fvec4 v = *(const fvec4*)(p + 4);
  bf16x8 r;
  r[0] = (bf16)u[0]; r[1] = (bf16)u[1]; r[2] = (bf16)u[2]; r[3] = (bf16)u[3];
  r[4] = (bf16)v[0]; r[5] = (bf16)v[1]; r[6] = (bf16)v[2]; r[7] = (bf16)v[3];
  return r;
}

// ---------------------------------------------------------------------------
// Fused fp32 -> bf16 bulk convert (8 elems/thread). grid 6144 x 256 exact.
// ---------------------------------------------------------------------------
__global__ void cvt_all(const float* __restrict__ x, const float* __restrict__ wq,
                        const float* __restrict__ wp, bf16* __restrict__ xb,
                        bf16* __restrict__ wqb, bf16* __restrict__ wpb) {
  int i = blockIdx.x * 256 + threadIdx.x;
  const float* s;
  bf16* d;
  int off;
  if (i < 1048576)      { s = x;  d = xb;  off = i; }
  else if (i < 1441792) { s = wq; d = wqb; off = i - 1048576; }
  else                  { s = wp; d = wpb; off = i - 1441792; }
  *(bf16x8*)(d + (size_t)off * 8) = cvt8(s + (size_t)off * 8);
}

// ---------------------------------------------------------------------------
// Shared epilogue: Q,K as [bh][t][64]; V TRANSPOSED as [bh][d][t].
// ---------------------------------------------------------------------------
__device__ __forceinline__ void qkv_scatter(const f32x4 acc[4][4], int m0, int n0,
                                            int wm, int wn, int quad, int l15,
                                            bf16* Qo, bf16* Ko, bf16* Vo) {
  const int which = n0 >> 10;  // 0=Q 1=K 2=V
  if (which == 2) {
#pragma unroll
    for (int i = 0; i < 4; ++i) {
      const int m = m0 + wm + i * 16 + quad * 4;
      const int b = m >> 11;
      const int t = m & 2047;
#pragma unroll
      for (int j = 0; j < 4; ++j) {
        const int n1 = (n0 + wn + j * 16 + l15) & 1023;
        const int h  = n1 >> 6;
        const int d  = n1 & 63;
        bf16x4 v;
#pragma unroll
        for (int r = 0; r < 4; ++r) v[r] = (bf16)acc[i][j][r];
        *(bf16x4*)(Vo + ((size_t)(b * 16 + h) * 64 + d) * 2048 + t) = v;
      }
    }
    return;
  }
  bf16* dst = (which == 0) ? Qo : Ko;
  const float scale = (which == 0) ? QSCALE : 1.0f;
#pragma unroll
  for (int i = 0; i < 4; ++i) {
    const int m = m0 + wm + i * 16 + quad * 4;
#pragma unroll
    for (int j = 0; j < 4; ++j) {
      const int n  = n0 + wn + j * 16 + l15;
      const int n1 = n & 1023;
      const int h  = n1 >> 6;
      const int d  = n1 & 63;
#pragma unroll
      for (int r = 0; r < 4; ++r) {
        const int mm = m + r;
        const int b  = mm >> 11;
        const int t  = mm & 2047;
        dst[(((size_t)(b * 16 + h)) * 2048 + t) * 64 + d] =
            (bf16)(acc[i][j][r] * scale);
      }
    }
  }
}

// ---------------------------------------------------------------------------
// QKV GEMM, bf16, 3-buffer counted-vmcnt pipeline. grid (24,64).
// XCD swizzle: XCD c owns n-panels {3c,3c+1,3c+2}.
// ---------------------------------------------------------------------------
__global__ __launch_bounds__(256, 3)
void gemm_qkv_a(const bf16* __restrict__ A, const bf16* __restrict__ B,
                bf16* __restrict__ Qo, bf16* __restrict__ Ko,
                bf16* __restrict__ Vo) {
  __shared__ __align__(16) bf16 As[3 * 128 * 32];   // 24KB, 3 rotating bufs
  __shared__ __align__(16) bf16 Bs[3 * 128 * 32];   // 24KB
  const int K = 1024;

  const int tid  = threadIdx.x;
  const int lane = tid & 63;
  const int wave = tid >> 6;
  const int quad = lane >> 4;
  const int l15  = lane & 15;
  const int wm   = (wave >> 1) * 64;
  const int wn   = (wave & 1) * 64;

  const int lin = (int)blockIdx.x + (int)blockIdx.y * 24;
  const int xcd = lin & 7;
  const int sl  = lin >> 3;
  const int n0  = (xcd * 3 + (sl % 3)) * 128;
  const int m0  = (sl / 3) * 128;

  f32x4 acc[4][4];
#pragma unroll
  for (int i = 0; i < 4; ++i)
#pragma unroll
    for (int j = 0; j < 4; ++j) acc[i][j] = f32x4{0.f, 0.f, 0.f, 0.f};

  const int r0 = tid >> 2;
  const int c0 = (tid & 3) * 8;
  const bf16* ag0 = A + (size_t)(m0 + r0) * K + c0;
  const bf16* ag1 = A + (size_t)(m0 + 64 + r0) * K + c0;
  const bf16* bg0 = B + (size_t)(n0 + r0) * K + c0;
  const bf16* bg1 = B + (size_t)(n0 + 64 + r0) * K + c0;
  const int lo0 = (wave * 64) * 8;
  const int lo1 = (256 + wave * 64) * 8;

  const int afb = (wm + l15) * 64 + quad * 16;
  const int bfb = (wn + l15) * 64 + quad * 16;

  // prologue: stage K-step 0 -> buf0, K-step 1 -> buf1 (8 loads in flight)
  async_ld16(ag0, As + lo0);
  async_ld16(ag1, As + lo1);
  async_ld16(bg0, Bs + lo0);
  async_ld16(bg1, Bs + lo1);
  ag0 += 32; ag1 += 32; bg0 += 32; bg1 += 32;
  async_ld16(ag0, As + 4096 + lo0);
  async_ld16(ag1, As + 4096 + lo1);
  async_ld16(bg0, Bs + 4096 + lo0);
  async_ld16(bg1, Bs + 4096 + lo1);
  ag0 += 32; ag1 += 32; bg0 += 32; bg1 += 32;
  asm volatile("s_waitcnt vmcnt(4)" ::: "memory");  // buf0 landed
  __builtin_amdgcn_s_barrier();
  __builtin_amdgcn_sched_barrier(0);

  int cure = 0;      // elem offset of current buffer (0/4096/8192)
  int nxte = 8192;   // elem offset of buffer for tile it+2
  for (int it = 0; it < 32; ++it) {
    if (it < 30) {   // stage tile it+2 (stays in flight across the barrier)
      async_ld16(ag0, As + nxte + lo0);
      async_ld16(ag1, As + nxte + lo1);
      async_ld16(bg0, Bs + nxte + lo0);
      async_ld16(bg1, Bs + nxte + lo1);
      ag0 += 32; ag1 += 32; bg0 += 32; bg1 += 32;
    }

    const char* pA = (const char*)As + cure * 2 + afb;
    const char* pB = (const char*)Bs + cure * 2 + bfb;
    bf16x8 af[4], bfr[4];
#pragma unroll
    for (int i = 0; i < 4; ++i) af[i] = *(const bf16x8*)(pA + i * 1024);
#pragma unroll
    for (int j = 0; j < 4; ++j) bfr[j] = *(const bf16x8*)(pB + j * 1024);
#pragma unroll
    for (int i = 0; i < 4; ++i)
#pragma unroll
      for (int j = 0; j < 4; ++j)
        acc[i][j] = MFMA16(af[i], bfr[j], acc[i][j]);

    // counted wait: my tile-(it+1) loads (4 oldest) landed; it+2's stay out.
    if (it < 30) asm volatile("s_waitcnt vmcnt(4)" ::: "memory");
    else         asm volatile("s_waitcnt vmcnt(0)" ::: "memory");
    __builtin_amdgcn_s_barrier();
    __builtin_amdgcn_sched_barrier(0);

    cure = (cure == 8192) ? 0 : cure + 4096;
    nxte = (nxte == 8192) ? 0 : nxte + 4096;
  }
  qkv_scatter(acc, m0, n0, wm, wn, quad, l15, Qo, Ko, Vo);
}

// ---------------------------------------------------------------------------
// QKV GEMM, fp32 cvt8 register-staging fallback. grid (24,64).
// ---------------------------------------------------------------------------
__global__ __launch_bounds__(256, 2)
void gemm_qkv_f(const float* __restrict__ A, const float* __restrict__ B,
                bf16* __restrict__ Qo, bf16* __restrict__ Ko,
                bf16* __restrict__ Vo) {
  __shared__ __align__(16) bf16 As[128 * 32];
  __shared__ __align__(16) bf16 Bs[128 * 32];
  const int K = 1024;

  const int tid  = threadIdx.x;
  const int lane = tid & 63;
  const int wave = tid >> 6;
  const int quad = lane >> 4;
  const int l15  = lane & 15;
  const int wm   = (wave >> 1) * 64;
  const int wn   = (wave & 1) * 64;

  const int lin = (int)blockIdx.x + (int)blockIdx.y * 24;
  const int xcd = lin & 7;
  const int sl  = lin >> 3;
  const int n0  = (xcd * 3 + (sl % 3)) * 128;
  const int m0  = (sl / 3) * 128;

  f32x4 acc[4][4];
#pragma unroll
  for (int i = 0; i < 4; ++i)
#pragma unroll
    for (int j = 0; j < 4; ++j) acc[i][j] = f32x4{0.f, 0.f, 0.f, 0.f};

  const int r0 = tid >> 2;
  const int c0 = (tid & 3) * 8;
  const size_t aoff0 = (size_t)(m0 + r0) * K + c0;
  const size_t aoff1 = (size_t)(m0 + 64 + r0) * K + c0;
  const size_t boff0 = (size_t)(n0 + r0) * K + c0;
  const size_t boff1 = (size_t)(n0 + 64 + r0) * K + c0;

  for (int k0 = 0; k0 < K; k0 += 32) {
    bf16x8 va0 = cvt8(A + aoff0 + k0);
    bf16x8 va1 = cvt8(A + aoff1 + k0);
    bf16x8 vb0 = cvt8(B + boff0 + k0);
    bf16x8 vb1 = cvt8(B + boff1 + k0);
    __syncthreads();
    *(bf16x8*)(As + tid * 8)        = va0;
    *(bf16x8*)(As + 2048 + tid * 8) = va1;
    *(bf16x8*)(Bs + tid * 8)        = vb0;
    *(bf16x8*)(Bs + 2048 + tid * 8) = vb1;
    __syncthreads();

    bf16x8 af[4], bfr[4];
#pragma unroll
    for (int i = 0; i < 4; ++i)
      af[i] = *(const bf16x8*)(As + (wm + i * 16 + l15) * 32 + quad * 8);
#pragma unroll
    for (int j = 0; j < 4; ++j)
      bfr[j] = *(const bf16x8*)(Bs + (wn + j * 16 + l15) * 32 + quad * 8);
#pragma unroll
    for (int i = 0; i < 4; ++i)
#pragma unroll
      for (int j = 0; j < 4; ++j)
        acc[i][j] = MFMA16(af[i], bfr[j], acc[i][j]);
  }
  qkv_scatter(acc, m0, n0, wm, wn, quad, l15, Qo, Ko, Vo);
}

// ---------------------------------------------------------------------------
// Flash attention — byte-identical to R8 passing version.
// grid (16,64), XCD-clustered remap; q-tiles {p, 31-p}.
// ---------------------------------------------------------------------------
__global__ __launch_bounds__(256, 3)
void attn(const bf16* __restrict__ Q, const bf16* __restrict__ Kk,
          const bf16* __restrict__ Vt, bf16* __restrict__ Y) {
  __shared__ __align__(16) bf16 Ks[2][64 * 64];   // [kv][d] swizzled
  __shared__ __align__(16) bf16 Vs[2][64 * 64];   // [d][kv] swizzled
  __shared__ __align__(16) bf16 Ps[4 * 16 * 64];  // per-wave P strips

  const int tid  = threadIdx.x;
  const int wave = tid >> 6;
  const int lane = tid & 63;
  const int quad = lane >> 4;
  const int l15  = lane & 15;

  const int lin  = (int)blockIdx.x + ((int)blockIdx.y << 4);
  const int slot = lin >> 3;
  const int bh   = (lin & 7) * 8 + (slot >> 4);
  const int p    = slot & 15;
  const int b    = bh >> 4;
  const int h    = bh & 15;

  const bf16* Qb = Q  + (size_t)bh * (2048 * 64);
  const bf16* Kb = Kk + (size_t)bh * (2048 * 64);   // [t][64]
  const bf16* Vb = Vt + (size_t)bh * (2048 * 64);   // [64][2048] (transposed)
  char* Pw = (char*)(Ps + wave * (16 * 64));        // 2KB per-wave strip

  const int r0s = wave * 8 + (lane >> 3);       // issue-0 row (0..31)
  const int r1s = r0s + 32;                     // issue-1 row (32..63)
  const int qch = lane & 7;
  const int co0 = (((qch ^ ((r0s & 7) ^ ((r0s >> 3) & 7)))) & 7) * 8;
  const int co1 = (((qch ^ ((r1s & 7) ^ ((r1s >> 3) & 7)))) & 7) * 8;
  const bf16* kg0 = Kb + (size_t)r0s * 64 + co0;    // + k0*64 per tile
  const bf16* kg1 = Kb + (size_t)r1s * 64 + co1;
  const bf16* vg0 = Vb + (size_t)r0s * 2048 + co0;  // + k0 per tile
  const bf16* vg1 = Vb + (size_t)r1s * 2048 + co1;
  const int ldsw = wave * 512;                  // wave-uniform elem offset

  // P strip addressing (bytes): row = l15 (128B), 16B chunk C ^= (l15&7).
  const int psx   = l15 & 7;
  const int prowb = l15 * 128;
  const int pr0   = prowb + ((quad ^ psx) << 4);        // PV A-frag k 0..31
  const int pr1   = prowb + (((4 + quad) ^ psx) << 4);  // PV A-frag k 32..63

  // Hoisted K/V fragment byte offsets (identical formula for K and V tiles).
  int fo0[4], fo1[4];
#pragma unroll
  for (int j = 0; j < 4; ++j) {
    const int kvr = j * 16 + l15;
    fo0[j] = swz_off(kvr, quad * 8) * 2;
    fo1[j] = swz_off(kvr, 32 + quad * 8) * 2;
  }
  // Hoisted P-strip write offsets (k = 16j + 4*quad .. +3).
  int pwo[4];
#pragma unroll
  for (int j = 0; j < 4; ++j)
    pwo[j] = prowb + ((((2 * j + (quad >> 1)) ^ psx) << 4) | ((quad & 1) << 3));

  const float NEG = -1e30f;

#pragma unroll 1
  for (int pass = 0; pass < 2; ++pass) {
    const int qt = pass ? (31 - p) : p;
    const int q0 = qt * 64;

    const bf16* qp = Qb + (size_t)(q0 + wave * 16 + l15) * 64 + quad * 8;
    bf16x8 qa0 = *(const bf16x8*)qp;
    bf16x8 qa1 = *(const bf16x8*)(qp + 32);

    f32x4 l4 = {0.f, 0.f, 0.f, 0.f};
    f32x4 o[4];
#pragma unroll
    for (int j = 0; j < 4; ++j) o[j] = f32x4{0.f, 0.f, 0.f, 0.f};

    // prologue: stage kv-tile 0 into buffer 0
    async_ld16(kg0, Ks[0] + ldsw);
    async_ld16(kg1, Ks[0] + 2048 + ldsw);
    async_ld16(vg0, Vs[0] + ldsw);
    async_ld16(vg1, Vs[0] + 2048 + ldsw);
    __syncthreads();

#pragma unroll 1
    for (int kt = 0; kt <= qt; ++kt) {
      const int cur = kt & 1;
      const int k0  = kt * 64;

      if (kt < qt) {
        const int kn = k0 + 64;
        async_ld16(kg0 + (size_t)kn * 64, Ks[cur ^ 1] + ldsw);
        async_ld16(kg1 + (size_t)kn * 64, Ks[cur ^ 1] + 2048 + ldsw);
        async_ld16(vg0 + kn, Vs[cur ^ 1] + ldsw);
        async_ld16(vg1 + kn, Vs[cur ^ 1] + 2048 + ldsw);
      }

      const char* kc = (const char*)Ks[cur];

      // S^T = K Q^T (log2 domain via QSCALE): lane -> q = l15,
      // k = k0 + 16j + 4*quad + r.
      f32x4 s[4];
      __builtin_amdgcn_s_setprio(1);
#pragma unroll
      for (int j = 0; j < 4; ++j) {
        bf16x8 k0f = *(const bf16x8*)(kc + fo0[j]);
        bf16x8 k1f = *(const bf16x8*)(kc + fo1[j]);
        f32x4 z = {0.f, 0.f, 0.f, 0.f};
        z = MFMA16(k0f, qa0, z);
        z = MFMA16(k1f, qa1, z);
        s[j] = z;
      }
      __builtin_amdgcn_s_setprio(0);

      if (kt == qt) {  // diagonal: causal mask (k_local > q_local)
        const int qloc = wave * 16 + l15;
#pragma unroll
        for (int j = 0; j < 4; ++j) {
#pragma unroll
          for (int r = 0; r < 4; ++r) {
            if (16 * j + 4 * quad + r > qloc) s[j][r] = NEG;
          }
        }
      }

      // p = exp2(s) via v_exp_f32; accumulate l partials
#pragma unroll
      for (int j = 0; j < 4; ++j) {
#pragma unroll
        for (int r = 0; r < 4; ++r) s[j][r] = exp2_fast(s[j][r]);
        l4 += s[j];
      }

      // P strip: 4 packed 8B writes (hoisted offsets).
#pragma unroll
      for (int j = 0; j < 4; ++j) {
        u32x2 pk;
        pk[0] = cvt_pk(s[j][0], s[j][1]);
        pk[1] = cvt_pk(s[j][2], s[j][3]);
        *(u32x2*)(Pw + pwo[j]) = pk;
      }

      bf16x8 pf0 = *(const bf16x8*)(Pw + pr0);
      bf16x8 pf1 = *(const bf16x8*)(Pw + pr1);

      // PV from V^T tile (same hoisted offsets as K)
      const char* vc = (const char*)Vs[cur];
      __builtin_amdgcn_s_setprio(1);
#pragma unroll
      for (int j = 0; j < 4; ++j) {
        bf16x8 vf0 = *(const bf16x8*)(vc + fo0[j]);
        bf16x8 vf1 = *(const bf16x8*)(vc + fo1[j]);
        o[j] = MFMA16(pf0, vf0, o[j]);
        o[j] = MFMA16(pf1, vf1, o[j]);
      }
      __builtin_amdgcn_s_setprio(0);

      __syncthreads();  // drains staging (vmcnt) + protects both buffers
    }

    // l: fold 4 components, reduce across quads, redistribute.
    float lf = (l4[0] + l4[1]) + (l4[2] + l4[3]);
    lf += __shfl_xor(lf, 16);
    lf += __shfl_xor(lf, 32);
    float inv[4];
#pragma unroll
    for (int r = 0; r < 4; ++r) inv[r] = 1.0f / __shfl(lf, quad * 4 + r);

#pragma unroll
    for (int j = 0; j < 4; ++j) {
      const int dcol = h * 64 + j * 16 + l15;
#pragma unroll
      for (int r = 0; r < 4; ++r) {
        const int trow = q0 + wave * 16 + quad * 4 + r;
        Y[((size_t)b * 2048 + trow) * 1024 + dcol] = (bf16)(o[j][r] * inv[r]);
      }
    }
  }
}

// ---------------------------------------------------------------------------
// Projection GEMM, bf16, 3-buffer counted-vmcnt pipeline: out fp32 = y*wpb^T.
// grid (8,64). XCD swizzle: XCD c owns m-panels 8c..8c+7.
// ---------------------------------------------------------------------------
__global__ __launch_bounds__(256, 3)
void gemm_proj_a(const bf16* __restrict__ A, const bf16* __restrict__ B,
                 float* __restrict__ C) {
  __shared__ __align__(16) bf16 As[3 * 128 * 32];
  __shared__ __align__(16) bf16 Bs[3 * 128 * 32];
  const int K = 1024, N = 1024;

  const int tid  = threadIdx.x;
  const int lane = tid & 63;
  const int wave = tid >> 6;
  const int quad = lane >> 4;
  const int l15  = lane & 15;
  const int wm   = (wave >> 1) * 64;
  const int wn   = (wave & 1) * 64;

  const int lin = (int)blockIdx.x + (int)blockIdx.y * 8;
  const int xcd = lin & 7;
  const int sl  = lin >> 3;
  const int m0  = (xcd * 8 + (sl & 7)) * 128;
  const int n0  = (sl >> 3) * 128;

  f32x4 acc[4][4];
#pragma unroll
  for (int i = 0; i < 4; ++i)
#pragma unroll
    for (int j = 0; j < 4; ++j) acc[i][j] = f32x4{0.f, 0.f, 0.f, 0.f};

  const int r0 = tid >> 2;
  const int c0 = (tid & 3) * 8;
  const bf16* ag0 = A + (size_t)(m0 + r0) * K + c0;
  const bf16* ag1 = A + (size_t)(m0 + 64 + r0) * K + c0;
  const bf16* bg0 = B + (size_t)(n0 + r0) * K + c0;
  const bf16* bg1 = B + (size_t)(n0 + 64 + r0) * K + c0;
  const int lo0 = (wave * 64) * 8;
  const int lo1 = (256 + wave * 64) * 8;

  const int afb = (wm + l15) * 64 + quad * 16;
  const int bfb = (wn + l15) * 64 + quad * 16;

  async_ld16(ag0, As + lo0);
  async_ld16(ag1, As + lo1);
  async_ld16(bg0, Bs + lo0);
  async_ld16(bg1, Bs + lo1);
  ag0 += 32; ag1 += 32; bg0 += 32; bg1 += 32;
  async_ld16(ag0, As + 4096 + lo0);
  async_ld16(ag1, As + 4096 + lo1);
  async_ld16(bg0, Bs + 4096 + lo0);
  async_ld16(bg1, Bs + 4096 + lo1);
  ag0 += 32; ag1 += 32; bg0 += 32; bg1 += 32;
  asm volatile("s_waitcnt vmcnt(4)" ::: "memory");
  __builtin_amdgcn_s_barrier();
  __builtin_amdgcn_sched_barrier(0);

  int cure = 0;
  int nxte = 8192;
  for (int it = 0; it < 32; ++it) {
    if (it < 30) {
      async_ld16(ag0, As + nxte + lo0);
      async_ld16(ag1, As + nxte + lo1);
      async_ld16(bg0, Bs + nxte + lo0);
      async_ld16(bg1, Bs + nxte + lo1);
      ag0 += 32; ag1 += 32; bg0 += 32; bg1 += 32;
    }

    const char* pA = (const char*)As + cure * 2 + afb;
    const char* pB = (const char*)Bs + cure * 2 + bfb;
    bf16x8 af[4], bfr[4];
#pragma unroll
    for (int i = 0; i < 4; ++i) af[i] = *(const bf16x8*)(pA + i * 1024);
#pragma unroll
    for (int j = 0; j < 4; ++j) bfr[j] = *(const bf16x8*)(pB + j * 1024);
#pragma unroll
    for (int i = 0; i < 4; ++i)
#pragma unroll
      for (int j = 0; j < 4; ++j)
        acc[i][j] = MFMA16(af[i], bfr[j], acc[i][j]);

    if (it < 30) asm volatile("s_waitcnt vmcnt(4)" ::: "memory");
    else         asm volatile("s_waitcnt vmcnt(0)" ::: "memory");
    __builtin_amdgcn_s_barrier();
    __builtin_amdgcn_sched_barrier(0);

    cure = (cure == 8192) ? 0 : cure + 4096;
    nxte = (nxte == 8192) ? 0 : nxte + 4096;
  }

#pragma unroll
  for (int i = 0; i < 4; ++i) {
    const int m = m0 + wm + i * 16 + quad * 4;
#pragma unroll
    for (int j = 0; j < 4; ++j) {
      const int n = n0 + wn + j * 16 + l15;
#pragma unroll
      for (int r = 0; r < 4; ++r)
        C[(size_t)(m + r) * N + n] = acc[i][j][r];
    }
  }
}

// ---------------------------------------------------------------------------
// Projection GEMM, fp32-B fallback. grid (8,64).
// ---------------------------------------------------------------------------
__global__ __launch_bounds__(256, 2)
void gemm_proj_f(const bf16* __restrict__ A, const float* __restrict__ B,
                 float* __restrict__ C) {
  __shared__ __align__(16) bf16 As[128 * 32];
  __shared__ __align__(16) bf16 Bs[128 * 32];
  const int K = 1024, N = 1024;

  const int tid  = threadIdx.x;
  const int lane = tid & 63;
  const int wave = tid >> 6;
  const int quad = lane >> 4;
  const int l15  = lane & 15;
  const int wm   = (wave >> 1) * 64;
  const int wn   = (wave & 1) * 64;

  const int lin = (int)blockIdx.x + (int)blockIdx.y * 8;
  const int xcd = lin & 7;
  const int sl  = lin >> 3;
  const int m0  = (xcd * 8 + (sl & 7)) * 128;
  const int n0  = (sl >> 3) * 128;

  f32x4 acc[4][4];
#pragma unroll
  for (int i = 0; i < 4; ++i)
#pragma unroll
    for (int j = 0; j < 4; ++j) acc[i][j] = f32x4{0.f, 0.f, 0.f, 0.f};

  const int r0 = tid >> 2;
  const int c0 = (tid & 3) * 8;
  const size_t aoff0 = (size_t)(m0 + r0) * K + c0;
  const size_t aoff1 = (size_t)(m0 + 64 + r0) * K + c0;
  const size_t boff0 = (size_t)(n0 + r0) * K + c0;
  const size_t boff1 = (size_t)(n0 + 64 + r0) * K + c0;

  for (int k0 = 0; k0 < K; k0 += 32) {
    bf16x8 va0 = *(const bf16x8*)(A + aoff0 + k0);
    bf16x8 va1 = *(const bf16x8*)(A + aoff1 + k0);
    bf16x8 vb0 = cvt8(B + boff0 + k0);
    bf16x8 vb1 = cvt8(B + boff1 + k0);
    __syncthreads();
    *(bf16x8*)(As + tid * 8)        = va0;
    *(bf16x8*)(As + 2048 + tid * 8) = va1;
    *(bf16x8*)(Bs + tid * 8)        = vb0;
    *(bf16x8*)(Bs + 2048 + tid * 8) = vb1;
    __syncthreads();

    bf16x8 af[4], bfr[4];
#pragma unroll
    for (int i = 0; i < 4; ++i)
      af[i] = *(const bf16x8*)(As + (wm + i * 16 + l15) * 32 + quad * 8);
#pragma unroll
    for (int j = 0; j < 4; ++j)
      bfr[j] = *(const bf16x8*)(Bs + (wn + j * 16 + l15) * 32 + quad * 8);
#pragma unroll
    for (int i = 0; i < 4; ++i)
#pragma unroll
      for (int j = 0; j < 4; ++j)
        acc[i][j] = MFMA16(af[i], bfr[j], acc[i][j]);
  }

#pragma unroll
  for (int i = 0; i < 4; ++i) {
    const int m = m0 + wm + i * 16 + quad * 4;
#pragma unroll
    for (int j = 0; j < 4; ++j) {
      const int n = n0 + wn + j * 16 + l15;
#pragma unroll
      for (int r = 0; r < 4; ++r)
        C[(size_t)(m + r) * N + n] = acc[i][j][r];
    }
  }
}

// ---------------------------------------------------------------------------
extern "C" void kernel_launch(void* const* d_in, const int* in_sizes, int n_in,
                              void* d_out, int out_size, void* d_ws, size_t ws_size,
                              hipStream_t stream) {
  const float* x  = nullptr;   // 8388608 elems
  const float* wq = nullptr;   // 3145728
  const float* wp = nullptr;   // 1048576
  for (int i = 0; i < n_in; ++i) {
    if      (in_sizes[i] == 8388608) x  = (const float*)d_in[i];
    else if (in_sizes[i] == 3145728) wq = (const float*)d_in[i];
    else if (in_sizes[i] == 1048576) wp = (const float*)d_in[i];
  }
  if (!x || !wq || !wp) {
    x = (const float*)d_in[0]; wq = (const float*)d_in[1]; wp = (const float*)d_in[2];
  }

  float* out = (float*)d_out;            // [4,2048,1024] fp32, written once
  const size_t NE = (size_t)4 * 16 * 2048 * 64;  // 8388608
  bf16* kb = (bf16*)d_ws;                // base 64MB: K, V^T, Q, y
  bf16* vb = kb + NE;                    // V^T: [bh][64][2048]
  bf16* qb = vb + NE;
  bf16* yb = qb + NE;
  bf16* xb  = yb + NE;                   // 8388608 elems
  bf16* wqb = xb + 8388608;              // 3145728
  bf16* wpb = wqb + 3145728;             // 1048576
  const size_t need = (4 * NE + 8388608 + 3145728 + 1048576) * sizeof(bf16);
  const bool ext = ws_size >= need;      // deterministic -> graph-safe

  if (ext) {
    cvt_all<<<6144, 256, 0, stream>>>(x, wq, wp, xb, wqb, wpb);
    gemm_qkv_a<<<dim3(24, 64), 256, 0, stream>>>(xb, wqb, qb, kb, vb);
  } else {
    gemm_qkv_f<<<dim3(24, 64), 256, 0, stream>>>(x, wq, qb, kb, vb);
  }

  attn<<<dim3(16, 64), 256, 0, stream>>>(qb, kb, vb, yb);

  if (ext) {
    gemm_proj_a<<<dim3(8, 64), 256, 0, stream>>>(yb, wpb, out);
  } else {
    gemm_proj_f<<<dim3(8, 64), 256, 0, stream>>>(yb, wp, out);
  }
}

// Round 10
// 239.540 us; speedup vs baseline: 1.0085x; 1.0085x over previous
//
#include <hip/hip_runtime.h>
#include <cstdint>
#include <cstddef>

// Pipeline v15. B=4, T=2048, D=1024, H=16, HD=64. Inputs fp32, output fp32.
// R10: GEMM LDS tiles were 8-way bank-conflicted ([row][32]bf16, 64B row
// stride: 16 rows hit 2 bank-groups). Fix = T2 chunk swizzle s(r)=(r>>1)&3,
// both-sides involution (rule #21): linear global_load_lds dest + source col
// ^= ((tid>>3)&3) + read chunk ^= ((l15>>1)&3). Verified 2 lanes/bank (free).
// Counted-vmcnt 3-buffer pipeline kept (R9). attn byte-identical to R8.

typedef __bf16 bf16;
typedef __bf16 bf16x4 __attribute__((ext_vector_type(4)));
typedef __bf16 bf16x8 __attribute__((ext_vector_type(8)));
typedef float  f32x4  __attribute__((ext_vector_type(4)));
typedef float  fvec4  __attribute__((ext_vector_type(4)));
typedef unsigned u32x2 __attribute__((ext_vector_type(2)));

typedef __attribute__((address_space(1))) const void global_cv;
typedef __attribute__((address_space(3))) void lds_v;

#define MFMA16(a, b, c) __builtin_amdgcn_mfma_f32_16x16x32_bf16((a), (b), (c), 0, 0, 0)

// Q scale: 1/sqrt(64) * log2(e)  (softmax done in exp2 domain)
#define QSCALE 0.18033688f

__device__ __forceinline__ void async_ld16(const bf16* g, bf16* l) {
  __builtin_amdgcn_global_load_lds((global_cv*)g, (lds_v*)l, 16, 0, 0);
}

// XOR chunk swizzle for [rows][64] bf16 LDS tiles (attn staging + frag reads).
__device__ __forceinline__ int swz_off(int row, int col) {
  int sr = (row & 7) ^ ((row >> 3) & 7);
  return row * 64 + ((((col >> 3) ^ sr) & 7) * 8) + (col & 7);
}

// packed f32x2 -> bf16x2
__device__ __forceinline__ unsigned cvt_pk(float lo, float hi) {
  unsigned r;
  asm("v_cvt_pk_bf16_f32 %0, %1, %2" : "=v"(r) : "v"(lo), "v"(hi));
  return r;
}

// exact v_exp_f32 (2^x), no libm fixup path
__device__ __forceinline__ float exp2_fast(float x) {
  float r;
  asm("v_exp_f32 %0, %1" : "=v"(r) : "v"(x));
  return r;
}

__device__ __forceinline__ bf16x8 cvt8(const float* p) {
  fvec4 u = *(const fvec4*)p;
  fvec4 v = *(const fvec4*)(p + 4);
  bf16x8 r;
  r[0] = (bf16)u[0]; r[1] = (bf16)u[1]; r[2] = (bf16)u[2]; r[3] = (bf16)u[3];
  r[4] = (bf16)v[0]; r[5] = (bf16)v[1]; r[6] = (bf16)v[2]; r[7] = (bf16)v[3];
  return r;
}

// ---------------------------------------------------------------------------
// Fused fp32 -> bf16 bulk convert (8 elems/thread). grid 6144 x 256 exact.
// ---------------------------------------------------------------------------
__global__ void cvt_all(const float* __restrict__ x, const float* __restrict__ wq,
                        const float* __restrict__ wp, bf16* __restrict__ xb,
                        bf16* __restrict__ wqb, bf16* __restrict__ wpb) {
  int i = blockIdx.x * 256 + threadIdx.x;
  const float* s;
  bf16* d;
  int off;
  if (i < 1048576)      { s = x;  d = xb;  off = i; }
  else if (i < 1441792) { s = wq; d = wqb; off = i - 1048576; }
  else                  { s = wp; d = wpb; off = i - 1441792; }
  *(bf16x8*)(d + (size_t)off * 8) = cvt8(s + (size_t)off * 8);
}

// ---------------------------------------------------------------------------
// Shared epilogue: Q,K as [bh][t][64]; V TRANSPOSED as [bh][d][t].
// ---------------------------------------------------------------------------
__device__ __forceinline__ void qkv_scatter(const f32x4 acc[4][4], int m0, int n0,
                                            int wm, int wn, int quad, int l15,
                                            bf16* Qo, bf16* Ko, bf16* Vo) {
  const int which = n0 >> 10;  // 0=Q 1=K 2=V
  if (which == 2) {
#pragma unroll
    for (int i = 0; i < 4; ++i) {
      const int m = m0 + wm + i * 16 + quad * 4;
      const int b = m >> 11;
      const int t = m & 2047;
#pragma unroll
      for (int j = 0; j < 4; ++j) {
        const int n1 = (n0 + wn + j * 16 + l15) & 1023;
        const int h  = n1 >> 6;
        const int d  = n1 & 63;
        bf16x4 v;
#pragma unroll
        for (int r = 0; r < 4; ++r) v[r] = (bf16)acc[i][j][r];
        *(bf16x4*)(Vo + ((size_t)(b * 16 + h) * 64 + d) * 2048 + t) = v;
      }
    }
    return;
  }
  bf16* dst = (which == 0) ? Qo : Ko;
  const float scale = (which == 0) ? QSCALE : 1.0f;
#pragma unroll
  for (int i = 0; i < 4; ++i) {
    const int m = m0 + wm + i * 16 + quad * 4;
#pragma unroll
    for (int j = 0; j < 4; ++j) {
      const int n  = n0 + wn + j * 16 + l15;
      const int n1 = n & 1023;
      const int h  = n1 >> 6;
      const int d  = n1 & 63;
#pragma unroll
      for (int r = 0; r < 4; ++r) {
        const int mm = m + r;
        const int b  = mm >> 11;
        const int t  = mm & 2047;
        dst[(((size_t)(b * 16 + h)) * 2048 + t) * 64 + d] =
            (bf16)(acc[i][j][r] * scale);
      }
    }
  }
}

// ---------------------------------------------------------------------------
// QKV GEMM, bf16, 3-buffer counted-vmcnt pipeline + T2 LDS swizzle.
// grid (24,64). XCD swizzle: XCD c owns n-panels {3c,3c+1,3c+2}.
// ---------------------------------------------------------------------------
__global__ __launch_bounds__(256, 3)
void gemm_qkv_a(const bf16* __restrict__ A, const bf16* __restrict__ B,
                bf16* __restrict__ Qo, bf16* __restrict__ Ko,
                bf16* __restrict__ Vo) {
  __shared__ __align__(16) bf16 As[3 * 128 * 32];   // 24KB, 3 rotating bufs
  __shared__ __align__(16) bf16 Bs[3 * 128 * 32];   // 24KB
  const int K = 1024;

  const int tid  = threadIdx.x;
  const int lane = tid & 63;
  const int wave = tid >> 6;
  const int quad = lane >> 4;
  const int l15  = lane & 15;
  const int wm   = (wave >> 1) * 64;
  const int wn   = (wave & 1) * 64;

  const int lin = (int)blockIdx.x + (int)blockIdx.y * 24;
  const int xcd = lin & 7;
  const int sl  = lin >> 3;
  const int n0  = (xcd * 3 + (sl % 3)) * 128;
  const int m0  = (sl / 3) * 128;

  f32x4 acc[4][4];
#pragma unroll
  for (int i = 0; i < 4; ++i)
#pragma unroll
    for (int j = 0; j < 4; ++j) acc[i][j] = f32x4{0.f, 0.f, 0.f, 0.f};

  const int r0 = tid >> 2;
  // T2 swizzle: LDS chunk (tid&3) of row r holds global chunk (tid&3)^s(r),
  // s(r) = (r>>1)&3 = (tid>>3)&3. Involution; s(r+64)=s(r).
  const int c0 = (((tid & 3) ^ ((tid >> 3) & 3)) * 8);
  const bf16* ag0 = A + (size_t)(m0 + r0) * K + c0;
  const bf16* ag1 = A + (size_t)(m0 + 64 + r0) * K + c0;
  const bf16* bg0 = B + (size_t)(n0 + r0) * K + c0;
  const bf16* bg1 = B + (size_t)(n0 + 64 + r0) * K + c0;
  const int lo0 = (wave * 64) * 8;
  const int lo1 = (256 + wave * 64) * 8;

  // frag read: row R = w*+i*16+l15, chunk quad^s(R); s(R)=(l15>>1)&3.
  const int rsw = ((quad ^ ((l15 >> 1) & 3)) * 16);
  const int afb = (wm + l15) * 64 + rsw;
  const int bfb = (wn + l15) * 64 + rsw;

  // prologue: stage K-step 0 -> buf0, K-step 1 -> buf1 (8 loads in flight)
  async_ld16(ag0, As + lo0);
  async_ld16(ag1, As + lo1);
  async_ld16(bg0, Bs + lo0);
  async_ld16(bg1, Bs + lo1);
  ag0 += 32; ag1 += 32; bg0 += 32; bg1 += 32;
  async_ld16(ag0, As + 4096 + lo0);
  async_ld16(ag1, As + 4096 + lo1);
  async_ld16(bg0, Bs + 4096 + lo0);
  async_ld16(bg1, Bs + 4096 + lo1);
  ag0 += 32; ag1 += 32; bg0 += 32; bg1 += 32;
  asm volatile("s_waitcnt vmcnt(4)" ::: "memory");  // buf0 landed
  __builtin_amdgcn_s_barrier();
  __builtin_amdgcn_sched_barrier(0);

  int cure = 0;      // elem offset of current buffer (0/4096/8192)
  int nxte = 8192;   // elem offset of buffer for tile it+2
  for (int it = 0; it < 32; ++it) {
    if (it < 30) {   // stage tile it+2 (stays in flight across the barrier)
      async_ld16(ag0, As + nxte + lo0);
      async_ld16(ag1, As + nxte + lo1);
      async_ld16(bg0, Bs + nxte + lo0);
      async_ld16(bg1, Bs + nxte + lo1);
      ag0 += 32; ag1 += 32; bg0 += 32; bg1 += 32;
    }

    const char* pA = (const char*)As + cure * 2 + afb;
    const char* pB = (const char*)Bs + cure * 2 + bfb;
    bf16x8 af[4], bfr[4];
#pragma unroll
    for (int i = 0; i < 4; ++i) af[i] = *(const bf16x8*)(pA + i * 1024);
#pragma unroll
    for (int j = 0; j < 4; ++j) bfr[j] = *(const bf16x8*)(pB + j * 1024);
#pragma unroll
    for (int i = 0; i < 4; ++i)
#pragma unroll
      for (int j = 0; j < 4; ++j)
        acc[i][j] = MFMA16(af[i], bfr[j], acc[i][j]);

    // counted wait: my tile-(it+1) loads (4 oldest) landed; it+2's stay out.
    if (it < 30) asm volatile("s_waitcnt vmcnt(4)" ::: "memory");
    else         asm volatile("s_waitcnt vmcnt(0)" ::: "memory");
    __builtin_amdgcn_s_barrier();
    __builtin_amdgcn_sched_barrier(0);

    cure = (cure == 8192) ? 0 : cure + 4096;
    nxte = (nxte == 8192) ? 0 : nxte + 4096;
  }
  qkv_scatter(acc, m0, n0, wm, wn, quad, l15, Qo, Ko, Vo);
}

// ---------------------------------------------------------------------------
// QKV GEMM, fp32 cvt8 register-staging fallback. grid (24,64).
// ---------------------------------------------------------------------------
__global__ __launch_bounds__(256, 2)
void gemm_qkv_f(const float* __restrict__ A, const float* __restrict__ B,
                bf16* __restrict__ Qo, bf16* __restrict__ Ko,
                bf16* __restrict__ Vo) {
  __shared__ __align__(16) bf16 As[128 * 32];
  __shared__ __align__(16) bf16 Bs[128 * 32];
  const int K = 1024;

  const int tid  = threadIdx.x;
  const int lane = tid & 63;
  const int wave = tid >> 6;
  const int quad = lane >> 4;
  const int l15  = lane & 15;
  const int wm   = (wave >> 1) * 64;
  const int wn   = (wave & 1) * 64;

  const int lin = (int)blockIdx.x + (int)blockIdx.y * 24;
  const int xcd = lin & 7;
  const int sl  = lin >> 3;
  const int n0  = (xcd * 3 + (sl % 3)) * 128;
  const int m0  = (sl / 3) * 128;

  f32x4 acc[4][4];
#pragma unroll
  for (int i = 0; i < 4; ++i)
#pragma unroll
    for (int j = 0; j < 4; ++j) acc[i][j] = f32x4{0.f, 0.f, 0.f, 0.f};

  const int r0 = tid >> 2;
  const int c0 = (tid & 3) * 8;
  const size_t aoff0 = (size_t)(m0 + r0) * K + c0;
  const size_t aoff1 = (size_t)(m0 + 64 + r0) * K + c0;
  const size_t boff0 = (size_t)(n0 + r0) * K + c0;
  const size_t boff1 = (size_t)(n0 + 64 + r0) * K + c0;

  for (int k0 = 0; k0 < K; k0 += 32) {
    bf16x8 va0 = cvt8(A + aoff0 + k0);
    bf16x8 va1 = cvt8(A + aoff1 + k0);
    bf16x8 vb0 = cvt8(B + boff0 + k0);
    bf16x8 vb1 = cvt8(B + boff1 + k0);
    __syncthreads();
    *(bf16x8*)(As + tid * 8)        = va0;
    *(bf16x8*)(As + 2048 + tid * 8) = va1;
    *(bf16x8*)(Bs + tid * 8)        = vb0;
    *(bf16x8*)(Bs + 2048 + tid * 8) = vb1;
    __syncthreads();

    bf16x8 af[4], bfr[4];
#pragma unroll
    for (int i = 0; i < 4; ++i)
      af[i] = *(const bf16x8*)(As + (wm + i * 16 + l15) * 32 + quad * 8);
#pragma unroll
    for (int j = 0; j < 4; ++j)
      bfr[j] = *(const bf16x8*)(Bs + (wn + j * 16 + l15) * 32 + quad * 8);
#pragma unroll
    for (int i = 0; i < 4; ++i)
#pragma unroll
      for (int j = 0; j < 4; ++j)
        acc[i][j] = MFMA16(af[i], bfr[j], acc[i][j]);
  }
  qkv_scatter(acc, m0, n0, wm, wn, quad, l15, Qo, Ko, Vo);
}

// ---------------------------------------------------------------------------
// Flash attention — byte-identical to R8 passing version.
// grid (16,64), XCD-clustered remap; q-tiles {p, 31-p}.
// ---------------------------------------------------------------------------
__global__ __launch_bounds__(256, 3)
void attn(const bf16* __restrict__ Q, const bf16* __restrict__ Kk,
          const bf16* __restrict__ Vt, bf16* __restrict__ Y) {
  __shared__ __align__(16) bf16 Ks[2][64 * 64];   // [kv][d] swizzled
  __shared__ __align__(16) bf16 Vs[2][64 * 64];   // [d][kv] swizzled
  __shared__ __align__(16) bf16 Ps[4 * 16 * 64];  // per-wave P strips

  const int tid  = threadIdx.x;
  const int wave = tid >> 6;
  const int lane = tid & 63;
  const int quad = lane >> 4;
  const int l15  = lane & 15;

  const int lin  = (int)blockIdx.x + ((int)blockIdx.y << 4);
  const int slot = lin >> 3;
  const int bh   = (lin & 7) * 8 + (slot >> 4);
  const int p    = slot & 15;
  const int b    = bh >> 4;
  const int h    = bh & 15;

  const bf16* Qb = Q  + (size_t)bh * (2048 * 64);
  const bf16* Kb = Kk + (size_t)bh * (2048 * 64);   // [t][64]
  const bf16* Vb = Vt + (size_t)bh * (2048 * 64);   // [64][2048] (transposed)
  char* Pw = (char*)(Ps + wave * (16 * 64));        // 2KB per-wave strip

  const int r0s = wave * 8 + (lane >> 3);       // issue-0 row (0..31)
  const int r1s = r0s + 32;                     // issue-1 row (32..63)
  const int qch = lane & 7;
  const int co0 = (((qch ^ ((r0s & 7) ^ ((r0s >> 3) & 7)))) & 7) * 8;
  const int co1 = (((qch ^ ((r1s & 7) ^ ((r1s >> 3) & 7)))) & 7) * 8;
  const bf16* kg0 = Kb + (size_t)r0s * 64 + co0;    // + k0*64 per tile
  const bf16* kg1 = Kb + (size_t)r1s * 64 + co1;
  const bf16* vg0 = Vb + (size_t)r0s * 2048 + co0;  // + k0 per tile
  const bf16* vg1 = Vb + (size_t)r1s * 2048 + co1;
  const int ldsw = wave * 512;                  // wave-uniform elem offset

  // P strip addressing (bytes): row = l15 (128B), 16B chunk C ^= (l15&7).
  const int psx   = l15 & 7;
  const int prowb = l15 * 128;
  const int pr0   = prowb + ((quad ^ psx) << 4);        // PV A-frag k 0..31
  const int pr1   = prowb + (((4 + quad) ^ psx) << 4);  // PV A-frag k 32..63

  // Hoisted K/V fragment byte offsets (identical formula for K and V tiles).
  int fo0[4], fo1[4];
#pragma unroll
  for (int j = 0; j < 4; ++j) {
    const int kvr = j * 16 + l15;
    fo0[j] = swz_off(kvr, quad * 8) * 2;
    fo1[j] = swz_off(kvr, 32 + quad * 8) * 2;
  }
  // Hoisted P-strip write offsets (k = 16j + 4*quad .. +3).
  int pwo[4];
#pragma unroll
  for (int j = 0; j < 4; ++j)
    pwo[j] = prowb + ((((2 * j + (quad >> 1)) ^ psx) << 4) | ((quad & 1) << 3));

  const float NEG = -1e30f;

#pragma unroll 1
  for (int pass = 0; pass < 2; ++pass) {
    const int qt = pass ? (31 - p) : p;
    const int q0 = qt * 64;

    const bf16* qp = Qb + (size_t)(q0 + wave * 16 + l15) * 64 + quad * 8;
    bf16x8 qa0 = *(const bf16x8*)qp;
    bf16x8 qa1 = *(const bf16x8*)(qp + 32);

    f32x4 l4 = {0.f, 0.f, 0.f, 0.f};
    f32x4 o[4];
#pragma unroll
    for (int j = 0; j < 4; ++j) o[j] = f32x4{0.f, 0.f, 0.f, 0.f};

    // prologue: stage kv-tile 0 into buffer 0
    async_ld16(kg0, Ks[0] + ldsw);
    async_ld16(kg1, Ks[0] + 2048 + ldsw);
    async_ld16(vg0, Vs[0] + ldsw);
    async_ld16(vg1, Vs[0] + 2048 + ldsw);
    __syncthreads();

#pragma unroll 1
    for (int kt = 0; kt <= qt; ++kt) {
      const int cur = kt & 1;
      const int k0  = kt * 64;

      if (kt < qt) {
        const int kn = k0 + 64;
        async_ld16(kg0 + (size_t)kn * 64, Ks[cur ^ 1] + ldsw);
        async_ld16(kg1 + (size_t)kn * 64, Ks[cur ^ 1] + 2048 + ldsw);
        async_ld16(vg0 + kn, Vs[cur ^ 1] + ldsw);
        async_ld16(vg1 + kn, Vs[cur ^ 1] + 2048 + ldsw);
      }

      const char* kc = (const char*)Ks[cur];

      // S^T = K Q^T (log2 domain via QSCALE): lane -> q = l15,
      // k = k0 + 16j + 4*quad + r.
      f32x4 s[4];
      __builtin_amdgcn_s_setprio(1);
#pragma unroll
      for (int j = 0; j < 4; ++j) {
        bf16x8 k0f = *(const bf16x8*)(kc + fo0[j]);
        bf16x8 k1f = *(const bf16x8*)(kc + fo1[j]);
        f32x4 z = {0.f, 0.f, 0.f, 0.f};
        z = MFMA16(k0f, qa0, z);
        z = MFMA16(k1f, qa1, z);
        s[j] = z;
      }
      __builtin_amdgcn_s_setprio(0);

      if (kt == qt) {  // diagonal: causal mask (k_local > q_local)
        const int qloc = wave * 16 + l15;
#pragma unroll
        for (int j = 0; j < 4; ++j) {
#pragma unroll
          for (int r = 0; r < 4; ++r) {
            if (16 * j + 4 * quad + r > qloc) s[j][r] = NEG;
          }
        }
      }

      // p = exp2(s) via v_exp_f32; accumulate l partials
#pragma unroll
      for (int j = 0; j < 4; ++j) {
#pragma unroll
        for (int r = 0; r < 4; ++r) s[j][r] = exp2_fast(s[j][r]);
        l4 += s[j];
      }

      // P strip: 4 packed 8B writes (hoisted offsets).
#pragma unroll
      for (int j = 0; j < 4; ++j) {
        u32x2 pk;
        pk[0] = cvt_pk(s[j][0], s[j][1]);
        pk[1] = cvt_pk(s[j][2], s[j][3]);
        *(u32x2*)(Pw + pwo[j]) = pk;
      }

      bf16x8 pf0 = *(const bf16x8*)(Pw + pr0);
      bf16x8 pf1 = *(const bf16x8*)(Pw + pr1);

      // PV from V^T tile (same hoisted offsets as K)
      const char* vc = (const char*)Vs[cur];
      __builtin_amdgcn_s_setprio(1);
#pragma unroll
      for (int j = 0; j < 4; ++j) {
        bf16x8 vf0 = *(const bf16x8*)(vc + fo0[j]);
        bf16x8 vf1 = *(const bf16x8*)(vc + fo1[j]);
        o[j] = MFMA16(pf0, vf0, o[j]);
        o[j] = MFMA16(pf1, vf1, o[j]);
      }
      __builtin_amdgcn_s_setprio(0);

      __syncthreads();  // drains staging (vmcnt) + protects both buffers
    }

    // l: fold 4 components, reduce across quads, redistribute.
    float lf = (l4[0] + l4[1]) + (l4[2] + l4[3]);
    lf += __shfl_xor(lf, 16);
    lf += __shfl_xor(lf, 32);
    float inv[4];
#pragma unroll
    for (int r = 0; r < 4; ++r) inv[r] = 1.0f / __shfl(lf, quad * 4 + r);

#pragma unroll
    for (int j = 0; j < 4; ++j) {
      const int dcol = h * 64 + j * 16 + l15;
#pragma unroll
      for (int r = 0; r < 4; ++r) {
        const int trow = q0 + wave * 16 + quad * 4 + r;
        Y[((size_t)b * 2048 + trow) * 1024 + dcol] = (bf16)(o[j][r] * inv[r]);
      }
    }
  }
}

// ---------------------------------------------------------------------------
// Projection GEMM, bf16, 3-buffer counted-vmcnt pipeline + T2 LDS swizzle.
// grid (8,64). XCD swizzle: XCD c owns m-panels 8c..8c+7.
// ---------------------------------------------------------------------------
__global__ __launch_bounds__(256, 3)
void gemm_proj_a(const bf16* __restrict__ A, const bf16* __restrict__ B,
                 float* __restrict__ C) {
  __shared__ __align__(16) bf16 As[3 * 128 * 32];
  __shared__ __align__(16) bf16 Bs[3 * 128 * 32];
  const int K = 1024, N = 1024;

  const int tid  = threadIdx.x;
  const int lane = tid & 63;
  const int wave = tid >> 6;
  const int quad = lane >> 4;
  const int l15  = lane & 15;
  const int wm   = (wave >> 1) * 64;
  const int wn   = (wave & 1) * 64;

  const int lin = (int)blockIdx.x + (int)blockIdx.y * 8;
  const int xcd = lin & 7;
  const int sl  = lin >> 3;
  const int m0  = (xcd * 8 + (sl & 7)) * 128;
  const int n0  = (sl >> 3) * 128;

  f32x4 acc[4][4];
#pragma unroll
  for (int i = 0; i < 4; ++i)
#pragma unroll
    for (int j = 0; j < 4; ++j) acc[i][j] = f32x4{0.f, 0.f, 0.f, 0.f};

  const int r0 = tid >> 2;
  const int c0 = (((tid & 3) ^ ((tid >> 3) & 3)) * 8);   // T2 source swizzle
  const bf16* ag0 = A + (size_t)(m0 + r0) * K + c0;
  const bf16* ag1 = A + (size_t)(m0 + 64 + r0) * K + c0;
  const bf16* bg0 = B + (size_t)(n0 + r0) * K + c0;
  const bf16* bg1 = B + (size_t)(n0 + 64 + r0) * K + c0;
  const int lo0 = (wave * 64) * 8;
  const int lo1 = (256 + wave * 64) * 8;

  const int rsw = ((quad ^ ((l15 >> 1) & 3)) * 16);      // T2 read swizzle
  const int afb = (wm + l15) * 64 + rsw;
  const int bfb = (wn + l15) * 64 + rsw;

  async_ld16(ag0, As + lo0);
  async_ld16(ag1, As + lo1);
  async_ld16(bg0, Bs + lo0);
  async_ld16(bg1, Bs + lo1);
  ag0 += 32; ag1 += 32; bg0 += 32; bg1 += 32;
  async_ld16(ag0, As + 4096 + lo0);
  async_ld16(ag1, As + 4096 + lo1);
  async_ld16(bg0, Bs + 4096 + lo0);
  async_ld16(bg1, Bs + 4096 + lo1);
  ag0 += 32; ag1 += 32; bg0 += 32; bg1 += 32;
  asm volatile("s_waitcnt vmcnt(4)" ::: "memory");
  __builtin_amdgcn_s_barrier();
  __builtin_amdgcn_sched_barrier(0);

  int cure = 0;
  int nxte = 8192;
  for (int it = 0; it < 32; ++it) {
    if (it < 30) {
      async_ld16(ag0, As + nxte + lo0);
      async_ld16(ag1, As + nxte + lo1);
      async_ld16(bg0, Bs + nxte + lo0);
      async_ld16(bg1, Bs + nxte + lo1);
      ag0 += 32; ag1 += 32; bg0 += 32; bg1 += 32;
    }

    const char* pA = (const char*)As + cure * 2 + afb;
    const char* pB = (const char*)Bs + cure * 2 + bfb;
    bf16x8 af[4], bfr[4];
#pragma unroll
    for (int i = 0; i < 4; ++i) af[i] = *(const bf16x8*)(pA + i * 1024);
#pragma unroll
    for (int j = 0; j < 4; ++j) bfr[j] = *(const bf16x8*)(pB + j * 1024);
#pragma unroll
    for (int i = 0; i < 4; ++i)
#pragma unroll
      for (int j = 0; j < 4; ++j)
        acc[i][j] = MFMA16(af[i], bfr[j], acc[i][j]);

    if (it < 30) asm volatile("s_waitcnt vmcnt(4)" ::: "memory");
    else         asm volatile("s_waitcnt vmcnt(0)" ::: "memory");
    __builtin_amdgcn_s_barrier();
    __builtin_amdgcn_sched_barrier(0);

    cure = (cure == 8192) ? 0 : cure + 4096;
    nxte = (nxte == 8192) ? 0 : nxte + 4096;
  }

#pragma unroll
  for (int i = 0; i < 4; ++i) {
    const int m = m0 + wm + i * 16 + quad * 4;
#pragma unroll
    for (int j = 0; j < 4; ++j) {
      const int n = n0 + wn + j * 16 + l15;
#pragma unroll
      for (int r = 0; r < 4; ++r)
        C[(size_t)(m + r) * N + n] = acc[i][j][r];
    }
  }
}

// ---------------------------------------------------------------------------
// Projection GEMM, fp32-B fallback. grid (8,64).
// ---------------------------------------------------------------------------
__global__ __launch_bounds__(256, 2)
void gemm_proj_f(const bf16* __restrict__ A, const float* __restrict__ B,
                 float* __restrict__ C) {
  __shared__ __align__(16) bf16 As[128 * 32];
  __shared__ __align__(16) bf16 Bs[128 * 32];
  const int K = 1024, N = 1024;

  const int tid  = threadIdx.x;
  const int lane = tid & 63;
  const int wave = tid >> 6;
  const int quad = lane >> 4;
  const int l15  = lane & 15;
  const int wm   = (wave >> 1) * 64;
  const int wn   = (wave & 1) * 64;

  const int lin = (int)blockIdx.x + (int)blockIdx.y * 8;
  const int xcd = lin & 7;
  const int sl  = lin >> 3;
  const int m0  = (xcd * 8 + (sl & 7)) * 128;
  const int n0  = (sl >> 3) * 128;

  f32x4 acc[4][4];
#pragma unroll
  for (int i = 0; i < 4; ++i)
#pragma unroll
    for (int j = 0; j < 4; ++j) acc[i][j] = f32x4{0.f, 0.f, 0.f, 0.f};

  const int r0 = tid >> 2;
  const int c0 = (tid & 3) * 8;
  const size_t aoff0 = (size_t)(m0 + r0) * K + c0;
  const size_t aoff1 = (size_t)(m0 + 64 + r0) * K + c0;
  const size_t boff0 = (size_t)(n0 + r0) * K + c0;
  const size_t boff1 = (size_t)(n0 + 64 + r0) * K + c0;

  for (int k0 = 0; k0 < K; k0 += 32) {
    bf16x8 va0 = *(const bf16x8*)(A + aoff0 + k0);
    bf16x8 va1 = *(const bf16x8*)(A + aoff1 + k0);
    bf16x8 vb0 = cvt8(B + boff0 + k0);
    bf16x8 vb1 = cvt8(B + boff1 + k0);
    __syncthreads();
    *(bf16x8*)(As + tid * 8)        = va0;
    *(bf16x8*)(As + 2048 + tid * 8) = va1;
    *(bf16x8*)(Bs + tid * 8)        = vb0;
    *(bf16x8*)(Bs + 2048 + tid * 8) = vb1;
    __syncthreads();

    bf16x8 af[4], bfr[4];
#pragma unroll
    for (int i = 0; i < 4; ++i)
      af[i] = *(const bf16x8*)(As + (wm + i * 16 + l15) * 32 + quad * 8);
#pragma unroll
    for (int j = 0; j < 4; ++j)
      bfr[j] = *(const bf16x8*)(Bs + (wn + j * 16 + l15) * 32 + quad * 8);
#pragma unroll
    for (int i = 0; i < 4; ++i)
#pragma unroll
      for (int j = 0; j < 4; ++j)
        acc[i][j] = MFMA16(af[i], bfr[j], acc[i][j]);
  }

#pragma unroll
  for (int i = 0; i < 4; ++i) {
    const int m = m0 + wm + i * 16 + quad * 4;
#pragma unroll
    for (int j = 0; j < 4; ++j) {
      const int n = n0 + wn + j * 16 + l15;
#pragma unroll
      for (int r = 0; r < 4; ++r)
        C[(size_t)(m + r) * N + n] = acc[i][j][r];
    }
  }
}

// ---------------------------------------------------------------------------
extern "C" void kernel_launch(void* const* d_in, const int* in_sizes, int n_in,
                              void* d_out, int out_size, void* d_ws, size_t ws_size,
                              hipStream_t stream) {
  const float* x  = nullptr;   // 8388608 elems
  const float* wq = nullptr;   // 3145728
  const float* wp = nullptr;   // 1048576
  for (int i = 0; i < n_in; ++i) {
    if      (in_sizes[i] == 8388608) x  = (const float*)d_in[i];
    else if (in_sizes[i] == 3145728) wq = (const float*)d_in[i];
    else if (in_sizes[i] == 1048576) wp = (const float*)d_in[i];
  }
  if (!x || !wq || !wp) {
    x = (const float*)d_in[0]; wq = (const float*)d_in[1]; wp = (const float*)d_in[2];
  }

  float* out = (float*)d_out;            // [4,2048,1024] fp32, written once
  const size_t NE = (size_t)4 * 16 * 2048 * 64;  // 8388608
  bf16* kb = (bf16*)d_ws;                // base 64MB: K, V^T, Q, y
  bf16* vb = kb + NE;                    // V^T: [bh][64][2048]
  bf16* qb = vb + NE;
  bf16* yb = qb + NE;
  bf16* xb  = yb + NE;                   // 8388608 elems
  bf16* wqb = xb + 8388608;              // 3145728
  bf16* wpb = wqb + 3145728;             // 1048576
  const size_t need = (4 * NE + 8388608 + 3145728 + 1048576) * sizeof(bf16);
  const bool ext = ws_size >= need;      // deterministic -> graph-safe

  if (ext) {
    cvt_all<<<6144, 256, 0, stream>>>(x, wq, wp, xb, wqb, wpb);
    gemm_qkv_a<<<dim3(24, 64), 256, 0, stream>>>(xb, wqb, qb, kb, vb);
  } else {
    gemm_qkv_f<<<dim3(24, 64), 256, 0, stream>>>(x, wq, qb, kb, vb);
  }

  attn<<<dim3(16, 64), 256, 0, stream>>>(qb, kb, vb, yb);

  if (ext) {
    gemm_proj_a<<<dim3(8, 64), 256, 0, stream>>>(yb, wpb, out);
  } else {
    gemm_proj_f<<<dim3(8, 64), 256, 0, stream>>>(yb, wp, out);
  }
}